// Round 3
// baseline (118785.657 us; speedup 1.0000x reference)
//
#include <hip/hip_runtime.h>
#include <stdint.h>

#define L4   250   // chase chunk length
#define GRP  50    // chunks per map-composition group
#define PF   16    // feat prefetch depth in k_chain

typedef float v2f __attribute__((ext_vector_type(2)));

// DPP ctrl codes (gfx9/CDNA): quad_perm imm, row_ror = 0x120|n (rows of 16)
#define QP_X1 0xB1   // quad_perm [1,0,3,2] = xor1
#define QP_X2 0x4E   // quad_perm [2,3,0,1] = xor2
#define ROR4  0x124
#define ROR8  0x128  // within row of 16: +8 == xor8 (direction-free)
#define ROR12 0x12C

#define DPPF(x, ctrl) __int_as_float(__builtin_amdgcn_mov_dpp(__float_as_int(x), (ctrl), 0xF, 0xF, true))

// ---------------------------------------------------------------------------
// One exact Viterbi value step, DPP-only.
// Lane i holds fv[i]. B[d] := fl(fv[i] + tr[i^d][i])  (d = n ^ i, static reg).
// Butterfly (exact fp32 max, order-free): bit3 (ror8), bit1 (qp), bit0 (qp),
// bit2 (ror4/ror12 + select; DP = "ror_n pulls from lane i+n").
// Returns max_p fl(fv[p] + tr[i][p])  on every lane.
// ---------------------------------------------------------------------------
template <bool DP>
__device__ __forceinline__ float vstep(float fv, const v2f* __restrict__ TR2, bool b2sel) {
  v2f fv2; fv2.x = fv; fv2.y = fv;
  v2f B01 = fv2 + TR2[0];  // d=0,1
  v2f B23 = fv2 + TR2[1];  // d=2,3
  v2f B45 = fv2 + TR2[2];  // d=4,5
  v2f B67 = fv2 + TR2[3];  // d=6,7
  v2f B89 = fv2 + TR2[4];  // d=8,9
  v2f Bab = fv2 + TR2[5];  // d=10,11
  v2f Bcd = fv2 + TR2[6];  // d=12,13
  v2f Bef = fv2 + TR2[7];  // d=14,15
  // stage bit3: d=0..7 <- partner(i^8) reg d|8   (ror8 == xor8)
  float c0 = fmaxf(B01.x, DPPF(B89.x, ROR8));
  float c1 = fmaxf(B01.y, DPPF(B89.y, ROR8));
  float c2 = fmaxf(B23.x, DPPF(Bab.x, ROR8));
  float c3 = fmaxf(B23.y, DPPF(Bab.y, ROR8));
  float c4 = fmaxf(B45.x, DPPF(Bcd.x, ROR8));
  float c5 = fmaxf(B45.y, DPPF(Bcd.y, ROR8));
  float c6 = fmaxf(B67.x, DPPF(Bef.x, ROR8));
  float c7 = fmaxf(B67.y, DPPF(Bef.y, ROR8));
  // stage bit1: d in {0,1,4,5} <- partner(i^2) reg d|2
  c0 = fmaxf(c0, DPPF(c2, QP_X2));
  c1 = fmaxf(c1, DPPF(c3, QP_X2));
  c4 = fmaxf(c4, DPPF(c6, QP_X2));
  c5 = fmaxf(c5, DPPF(c7, QP_X2));
  // stage bit0: d in {0,4} <- partner(i^1) reg d|1
  c0 = fmaxf(c0, DPPF(c1, QP_X1));
  c4 = fmaxf(c4, DPPF(c5, QP_X1));
  // stage bit2: d=0 <- partner(i^4) reg 4
  float ra = DPPF(c4, ROR4);    // DP: from i+4, else from i-4
  float rb = DPPF(c4, ROR12);   // DP: from i-4, else from i+4
  float pv;
  if (DP) pv = b2sel ? rb : ra; // bit2==1 lanes need i-4; bit2==0 need i+4
  else    pv = b2sel ? ra : rb;
  return fmaxf(c0, pv);
}

template <bool DP>
__device__ __forceinline__ void chain_run(const float* __restrict__ feats,
                                          float* __restrict__ FV,
                                          const v2f* __restrict__ TR2,
                                          int* __restrict__ last_tag, int T) {
  const int l = threadIdx.x;
  const int i = l & 15;
  const bool b2sel = ((i >> 2) & 1) != 0;

  float fv = 0.0f;
  FV[i] = 0.0f;  // FV[0] = zeros (replicated rows store same data to same addr)

  float fbuf[PF];
  #pragma unroll
  for (int u = 0; u < PF; ++u) {
    int idx = (u < T) ? u : (T - 1);
    fbuf[u] = feats[idx * 16 + i];
  }

  const char* pf_ptr = (const char*)(feats + (size_t)PF * 16 + i);
  char*       st_ptr = (char*)(FV + 16 + i);

  int Tm = (T >= 2 * PF) ? ((T - PF) / PF) * PF : 0;

  for (int t = 0; t < Tm; t += PF) {
    #pragma unroll
    for (int u = 0; u < PF; ++u) {
      float m = vstep<DP>(fv, TR2, b2sel);
      fv = m + fbuf[u];
      fbuf[u] = *(const float*)pf_ptr;  pf_ptr += 64;   // prefetch t+u+PF (valid: < T)
      *(float*)st_ptr = fv;             st_ptr += 64;   // FV[t+u+1][i]
    }
  }
  for (int t = Tm; t < T; ++t) {  // tail: direct loads
    float m = vstep<DP>(fv, TR2, b2sel);
    fv = m + feats[(size_t)t * 16 + i];
    FV[(size_t)(t + 1) * 16 + i] = fv;
  }

  // last_tag = argmax (first-index) of final fv
  float bv = __shfl(fv, 0, 64); int bi = 0;
  #pragma unroll
  for (int p = 1; p < 16; ++p) {
    float ov = __shfl(fv, p, 64);
    if (ov > bv) { bv = ov; bi = p; }
  }
  if (l == 0) *last_tag = bi;
}

// ---------------------------------------------------------------------------
// K1: value-only exact Viterbi forward chain. ONE wave, DPP-only hot loop.
// ---------------------------------------------------------------------------
__global__ __launch_bounds__(64)
void k_chain(const float* __restrict__ feats, const float* __restrict__ trans,
             float* __restrict__ FV, int* __restrict__ last_tag, int T) {
  const int l = threadIdx.x;
  const int i = l & 15;

  v2f TR2[8];
  #pragma unroll
  for (int k = 0; k < 8; ++k) {
    TR2[k].x = trans[((i ^ (2 * k)) << 4) + i];
    TR2[k].y = trans[((i ^ (2 * k + 1)) << 4) + i];
  }

  // Runtime probe of ROW_ROR direction: lane 0 sees value 4 if ror4 pulls from i+4.
  int pr = __builtin_amdgcn_mov_dpp(i, ROR4, 0xF, 0xF, true);
  bool dirplus = (__builtin_amdgcn_readfirstlane(pr) == 4);

  if (dirplus) chain_run<true >(feats, FV, TR2, last_tag, T);
  else         chain_run<false>(feats, FV, TR2, last_tag, T);
}

// ---------------------------------------------------------------------------
// K2: parallel backpointer recompute. Thread per t. Bit-identical argmax
// (strict >, first-index) from exact FV[t].
// ---------------------------------------------------------------------------
__global__ __launch_bounds__(256)
void k_bp(const float* __restrict__ FV, const float* __restrict__ trans,
          uint4* __restrict__ bp, int T) {
  __shared__ float str[256];
  const int tid = threadIdx.x;
  str[tid] = trans[tid];
  __syncthreads();
  const int t = blockIdx.x * blockDim.x + tid;
  if (t >= T) return;
  const float4* fr = (const float4*)(FV + (size_t)t * 16);
  float4 q0 = fr[0], q1 = fr[1], q2 = fr[2], q3 = fr[3];
  float fv[16] = {q0.x, q0.y, q0.z, q0.w, q1.x, q1.y, q1.z, q1.w,
                  q2.x, q2.y, q2.z, q2.w, q3.x, q3.y, q3.z, q3.w};
  uint32_t w[4];
  #pragma unroll
  for (int g = 0; g < 4; ++g) {
    uint32_t word = 0;
    #pragma unroll
    for (int s = 0; s < 4; ++s) {
      const int nn = 4 * g + s;
      float best = fv[0] + str[nn * 16 + 0];
      int bi = 0;
      #pragma unroll
      for (int p = 1; p < 16; ++p) {
        float v = fv[p] + str[nn * 16 + p];
        if (v > best) { best = v; bi = p; }
      }
      word |= (uint32_t)bi << (8 * s);
    }
    w[g] = word;
  }
  bp[t] = make_uint4(w[0], w[1], w[2], w[3]);
}

// ---------------------------------------------------------------------------
// K3: per-chunk 16-hypothesis backtrack (exact integer pointer chase).
// ---------------------------------------------------------------------------
__global__ __launch_bounds__(64)
void k_chase(const unsigned char* __restrict__ bp, unsigned char* __restrict__ st,
             unsigned char* __restrict__ maps, int T, int C) {
  const int tid = threadIdx.x;
  const int chunk = blockIdx.x * 4 + (tid >> 4);
  const int h = tid & 15;
  if (chunk >= C) return;
  const int a = chunk * L4;
  int b = a + L4; if (b > T) b = T;
  int cur = h;
  for (int t = b - 1; t >= a; --t) {
    cur = bp[(size_t)t * 16 + cur];
    st[(size_t)t * 16 + h] = (unsigned char)cur;
  }
  maps[chunk * 16 + h] = (unsigned char)cur;
}

// ---------------------------------------------------------------------------
// K4: compose GRP consecutive chunk maps into one super-map per group.
// ---------------------------------------------------------------------------
__global__ __launch_bounds__(64)
void k_group(const unsigned char* __restrict__ maps, unsigned char* __restrict__ sup,
             int C, int NG) {
  const int g = blockIdx.x;
  const int e = threadIdx.x;
  if (g >= NG || e >= 16) return;
  int hi = g * GRP + GRP - 1; if (hi > C - 1) hi = C - 1;
  int cur = e;
  for (int c = hi; c >= g * GRP; --c) cur = maps[c * 16 + cur];
  sup[g * 16 + e] = (unsigned char)cur;
}

// ---------------------------------------------------------------------------
// K5: resolve true tag at every chunk's end boundary.
// ---------------------------------------------------------------------------
__global__ __launch_bounds__(128)
void k_resolve(const unsigned char* __restrict__ maps, const unsigned char* __restrict__ sup,
               const int* __restrict__ last_tag, unsigned char* __restrict__ s_arr,
               int C, int NG) {
  __shared__ unsigned char Sg[4096];
  const int tid = threadIdx.x;
  if (tid == 0) {
    int cur = *last_tag;
    for (int g = NG - 1; g >= 0; --g) {
      Sg[g] = (unsigned char)cur;
      cur = sup[g * 16 + cur];
    }
  }
  __syncthreads();
  for (int g = tid; g < NG; g += blockDim.x) {
    int cur = Sg[g];
    int hi = g * GRP + GRP - 1; if (hi > C - 1) hi = C - 1;
    for (int c = hi; c >= g * GRP; --c) {
      s_arr[c] = (unsigned char)cur;
      cur = maps[c * 16 + cur];
    }
  }
}

// ---------------------------------------------------------------------------
// K6: emit out[t] = st[t*16 + s_arr[t / L4]] as int32.
// ---------------------------------------------------------------------------
__global__ void k_emit(const unsigned char* __restrict__ st,
                       const unsigned char* __restrict__ s_arr,
                       int* __restrict__ out, int T) {
  int t = blockIdx.x * blockDim.x + threadIdx.x;
  if (t < T) out[t] = (int)st[(size_t)t * 16 + s_arr[t / L4]];
}

extern "C" void kernel_launch(void* const* d_in, const int* in_sizes, int n_in,
                              void* d_out, int out_size, void* d_ws, size_t ws_size,
                              hipStream_t stream) {
  const float* feats = (const float*)d_in[0];   // [1, T, 16] fp32
  const float* trans = (const float*)d_in[1];   // [16, 16]  fp32
  int* out = (int*)d_out;                       // [T] int32

  const int T  = in_sizes[0] / 16;
  const int C  = (T + L4 - 1) / L4;
  const int NG = (C + GRP - 1) / GRP;

  char* ws = (char*)d_ws;
  float* FV           = (float*)ws;                                   // (T+1)*16 floats
  unsigned char* bp   = (unsigned char*)(FV + (size_t)(T + 1) * 16);  // T*16 B
  unsigned char* st   = bp + (size_t)T * 16;                          // T*16 B
  unsigned char* maps = st + (size_t)T * 16;                          // C*16
  unsigned char* sup  = maps + (size_t)C * 16;                        // NG*16
  unsigned char* sarr = sup + (size_t)NG * 16;                        // C
  int* last_tag = (int*)(((uintptr_t)(sarr + C) + 15) & ~(uintptr_t)15);
  size_t need = (size_t)((char*)(last_tag + 1) - ws);
  if (ws_size < need) return;  // insufficient scratch -> fail visibly

  k_chain<<<1, 64, 0, stream>>>(feats, trans, FV, last_tag, T);
  k_bp<<<(T + 255) / 256, 256, 0, stream>>>(FV, trans, (uint4*)bp, T);
  k_chase<<<(C + 3) / 4, 64, 0, stream>>>(bp, st, maps, T, C);
  k_group<<<NG, 64, 0, stream>>>(maps, sup, C, NG);
  k_resolve<<<1, 128, 0, stream>>>(maps, sup, last_tag, sarr, C, NG);
  const int thr = 256;
  k_emit<<<(T + thr - 1) / thr, thr, 0, stream>>>(st, sarr, out, T);
}

// Round 4
// 89454.633 us; speedup vs baseline: 1.3279x; 1.3279x over previous
//
#include <hip/hip_runtime.h>
#include <stdint.h>

#define L4   250   // chase chunk length
#define GRP  50    // chunks per map-composition group
#define PF   16    // feat prefetch depth (named registers) in k_chain

// ---------------------------------------------------------------------------
// Exact 16-wide max-reduce via fused DPP xor-butterfly, masks {8,7,3,1}:
//   row_ror:8        == lane i^8 (within row of 16)
//   row_half_mirror  == lane i^7
//   quad_perm:[3,2,1,0] == lane i^3
//   quad_perm:[1,0,3,2] == lane i^1
// {8,7,3,1} are linearly independent over GF(2)^4 -> full 16-lane reduction.
// Lane i holds b_d = fl(fv[i] + tr[i^d][i]); stage mask m folds d with d^m.
// All instruction distances on VALU-write -> DPP-read pairs are >= 2; s_nop
// guards cover the asm-entry and the final distance-2 case.
// Result (max over row i) lands in b0.
// ---------------------------------------------------------------------------
#define BTREE(b0,b1,b2,b3,b4,b5,b6,b7,b8,b9,b10,b11,b12,b13,b14,b15)          \
  asm("s_nop 1\n\t"                                                           \
      "v_max_f32_dpp %0, %8, %0  row_ror:8 row_mask:0xf bank_mask:0xf\n\t"    \
      "v_max_f32_dpp %1, %9, %1  row_ror:8 row_mask:0xf bank_mask:0xf\n\t"    \
      "v_max_f32_dpp %2, %10, %2 row_ror:8 row_mask:0xf bank_mask:0xf\n\t"    \
      "v_max_f32_dpp %3, %11, %3 row_ror:8 row_mask:0xf bank_mask:0xf\n\t"    \
      "v_max_f32_dpp %4, %12, %4 row_ror:8 row_mask:0xf bank_mask:0xf\n\t"    \
      "v_max_f32_dpp %5, %13, %5 row_ror:8 row_mask:0xf bank_mask:0xf\n\t"    \
      "v_max_f32_dpp %6, %14, %6 row_ror:8 row_mask:0xf bank_mask:0xf\n\t"    \
      "v_max_f32_dpp %7, %15, %7 row_ror:8 row_mask:0xf bank_mask:0xf\n\t"    \
      "v_max_f32_dpp %3, %4, %3  row_half_mirror row_mask:0xf bank_mask:0xf\n\t" \
      "v_max_f32_dpp %2, %5, %2  row_half_mirror row_mask:0xf bank_mask:0xf\n\t" \
      "v_max_f32_dpp %1, %6, %1  row_half_mirror row_mask:0xf bank_mask:0xf\n\t" \
      "v_max_f32_dpp %0, %7, %0  row_half_mirror row_mask:0xf bank_mask:0xf\n\t" \
      "v_max_f32_dpp %1, %2, %1  quad_perm:[3,2,1,0] row_mask:0xf bank_mask:0xf\n\t" \
      "v_max_f32_dpp %0, %3, %0  quad_perm:[3,2,1,0] row_mask:0xf bank_mask:0xf\n\t" \
      "s_nop 0\n\t"                                                           \
      "v_max_f32_dpp %0, %1, %0  quad_perm:[1,0,3,2] row_mask:0xf bank_mask:0xf" \
      : "+v"(b0), "+v"(b1), "+v"(b2), "+v"(b3),                               \
        "+v"(b4), "+v"(b5), "+v"(b6), "+v"(b7),                               \
        "+v"(b8), "+v"(b9), "+v"(b10), "+v"(b11),                             \
        "+v"(b12), "+v"(b13), "+v"(b14), "+v"(b15))

// One exact Viterbi value step. FB = prefetched feat[t][i]; u = slot index
// for immediate-offset addressing (u*64 bytes). Main-loop variant.
#define STEP(FB, u)  do {                                                     \
    float b0 = fv + tr0,  b1 = fv + tr1,  b2 = fv + tr2,  b3 = fv + tr3;      \
    float b4 = fv + tr4,  b5 = fv + tr5,  b6 = fv + tr6,  b7 = fv + tr7;      \
    float b8 = fv + tr8,  b9 = fv + tr9,  b10 = fv + tr10, b11 = fv + tr11;   \
    float b12 = fv + tr12, b13 = fv + tr13, b14 = fv + tr14, b15 = fv + tr15; \
    BTREE(b0,b1,b2,b3,b4,b5,b6,b7,b8,b9,b10,b11,b12,b13,b14,b15);             \
    fv = b0 + FB;                                                             \
    FB = pf[(u) * 16];                                                        \
    st[(u) * 16] = fv;                                                        \
  } while (0)

// ---------------------------------------------------------------------------
// K1: value-only exact Viterbi forward chain. ONE wave, fused-DPP hot loop,
// zero LDS ops, zero scratch arrays (all state in named VGPRs).
// Lane i (replicated x4 across the wave's four 16-lane rows) holds fv[i].
// Streams FV[t] (fv entering step t); FV[0] = zeros.
// ---------------------------------------------------------------------------
__global__ __launch_bounds__(64)
void k_chain(const float* __restrict__ feats, const float* __restrict__ trans,
             float* __restrict__ FV, int* __restrict__ last_tag, int T) {
  const int l = threadIdx.x;
  const int i = l & 15;

  // tr_d = trans[(i^d)][i]
  const float tr0  = trans[((i ^ 0)  << 4) + i];
  const float tr1  = trans[((i ^ 1)  << 4) + i];
  const float tr2  = trans[((i ^ 2)  << 4) + i];
  const float tr3  = trans[((i ^ 3)  << 4) + i];
  const float tr4  = trans[((i ^ 4)  << 4) + i];
  const float tr5  = trans[((i ^ 5)  << 4) + i];
  const float tr6  = trans[((i ^ 6)  << 4) + i];
  const float tr7  = trans[((i ^ 7)  << 4) + i];
  const float tr8  = trans[((i ^ 8)  << 4) + i];
  const float tr9  = trans[((i ^ 9)  << 4) + i];
  const float tr10 = trans[((i ^ 10) << 4) + i];
  const float tr11 = trans[((i ^ 11) << 4) + i];
  const float tr12 = trans[((i ^ 12) << 4) + i];
  const float tr13 = trans[((i ^ 13) << 4) + i];
  const float tr14 = trans[((i ^ 14) << 4) + i];
  const float tr15 = trans[((i ^ 15) << 4) + i];

  float fv = 0.0f;
  FV[i] = 0.0f;  // FV[0] = init (replicated lanes write same value/addr)

  // 16 named prefetch registers: f_u = feats[u][i]
  #define LD0(u) ((u) < T ? feats[(u) * 16 + i] : 0.0f)
  float f0 = LD0(0),  f1 = LD0(1),  f2 = LD0(2),  f3 = LD0(3);
  float f4 = LD0(4),  f5 = LD0(5),  f6 = LD0(6),  f7 = LD0(7);
  float f8 = LD0(8),  f9 = LD0(9),  f10 = LD0(10), f11 = LD0(11);
  float f12 = LD0(12), f13 = LD0(13), f14 = LD0(14), f15 = LD0(15);
  #undef LD0

  const float* pf = feats + (size_t)PF * 16 + i;  // prefetch base (t+PF)
  float*       st = FV + 16 + i;                  // store base (FV[t+1])

  const int Tm = (T >= 2 * PF) ? ((T - PF) / PF) * PF : 0;

  for (int t = 0; t < Tm; t += PF) {
    STEP(f0, 0);   STEP(f1, 1);   STEP(f2, 2);   STEP(f3, 3);
    STEP(f4, 4);   STEP(f5, 5);   STEP(f6, 6);   STEP(f7, 7);
    STEP(f8, 8);   STEP(f9, 9);   STEP(f10, 10); STEP(f11, 11);
    STEP(f12, 12); STEP(f13, 13); STEP(f14, 14); STEP(f15, 15);
    pf += PF * 16;
    st += PF * 16;
  }
  for (int t = Tm; t < T; ++t) {  // tail: direct loads
    float b0 = fv + tr0,  b1 = fv + tr1,  b2 = fv + tr2,  b3 = fv + tr3;
    float b4 = fv + tr4,  b5 = fv + tr5,  b6 = fv + tr6,  b7 = fv + tr7;
    float b8 = fv + tr8,  b9 = fv + tr9,  b10 = fv + tr10, b11 = fv + tr11;
    float b12 = fv + tr12, b13 = fv + tr13, b14 = fv + tr14, b15 = fv + tr15;
    BTREE(b0,b1,b2,b3,b4,b5,b6,b7,b8,b9,b10,b11,b12,b13,b14,b15);
    fv = b0 + feats[(size_t)t * 16 + i];
    FV[(size_t)(t + 1) * 16 + i] = fv;
  }

  // last_tag = argmax (first-index tie-break) of final fv
  float bv = __shfl(fv, 0, 64); int bi = 0;
  #pragma unroll
  for (int p = 1; p < 16; ++p) {
    float ov = __shfl(fv, p, 64);
    if (ov > bv) { bv = ov; bi = p; }
  }
  if (l == 0) *last_tag = bi;
}

// ---------------------------------------------------------------------------
// K2: parallel backpointer recompute. Thread per t. Bit-identical argmax
// (strict >, first-index) from exact FV[t].
// ---------------------------------------------------------------------------
__global__ __launch_bounds__(256)
void k_bp(const float* __restrict__ FV, const float* __restrict__ trans,
          uint4* __restrict__ bp, int T) {
  __shared__ float str[256];
  const int tid = threadIdx.x;
  str[tid] = trans[tid];
  __syncthreads();
  const int t = blockIdx.x * blockDim.x + tid;
  if (t >= T) return;
  const float4* fr = (const float4*)(FV + (size_t)t * 16);
  float4 q0 = fr[0], q1 = fr[1], q2 = fr[2], q3 = fr[3];
  float fv[16] = {q0.x, q0.y, q0.z, q0.w, q1.x, q1.y, q1.z, q1.w,
                  q2.x, q2.y, q2.z, q2.w, q3.x, q3.y, q3.z, q3.w};
  uint32_t w[4];
  #pragma unroll
  for (int g = 0; g < 4; ++g) {
    uint32_t word = 0;
    #pragma unroll
    for (int s = 0; s < 4; ++s) {
      const int nn = 4 * g + s;
      float best = fv[0] + str[nn * 16 + 0];
      int bi = 0;
      #pragma unroll
      for (int p = 1; p < 16; ++p) {
        float v = fv[p] + str[nn * 16 + p];
        if (v > best) { best = v; bi = p; }
      }
      word |= (uint32_t)bi << (8 * s);
    }
    w[g] = word;
  }
  bp[t] = make_uint4(w[0], w[1], w[2], w[3]);
}

// ---------------------------------------------------------------------------
// K3: per-chunk 16-hypothesis backtrack (exact integer pointer chase).
// ---------------------------------------------------------------------------
__global__ __launch_bounds__(64)
void k_chase(const unsigned char* __restrict__ bp, unsigned char* __restrict__ st,
             unsigned char* __restrict__ maps, int T, int C) {
  const int tid = threadIdx.x;
  const int chunk = blockIdx.x * 4 + (tid >> 4);
  const int h = tid & 15;
  if (chunk >= C) return;
  const int a = chunk * L4;
  int b = a + L4; if (b > T) b = T;
  int cur = h;
  for (int t = b - 1; t >= a; --t) {
    cur = bp[(size_t)t * 16 + cur];
    st[(size_t)t * 16 + h] = (unsigned char)cur;
  }
  maps[chunk * 16 + h] = (unsigned char)cur;
}

// ---------------------------------------------------------------------------
// K4: compose GRP consecutive chunk maps into one super-map per group.
// ---------------------------------------------------------------------------
__global__ __launch_bounds__(64)
void k_group(const unsigned char* __restrict__ maps, unsigned char* __restrict__ sup,
             int C, int NG) {
  const int g = blockIdx.x;
  const int e = threadIdx.x;
  if (g >= NG || e >= 16) return;
  int hi = g * GRP + GRP - 1; if (hi > C - 1) hi = C - 1;
  int cur = e;
  for (int c = hi; c >= g * GRP; --c) cur = maps[c * 16 + cur];
  sup[g * 16 + e] = (unsigned char)cur;
}

// ---------------------------------------------------------------------------
// K5: resolve true tag at every chunk's end boundary.
// ---------------------------------------------------------------------------
__global__ __launch_bounds__(128)
void k_resolve(const unsigned char* __restrict__ maps, const unsigned char* __restrict__ sup,
               const int* __restrict__ last_tag, unsigned char* __restrict__ s_arr,
               int C, int NG) {
  __shared__ unsigned char Sg[4096];
  const int tid = threadIdx.x;
  if (tid == 0) {
    int cur = *last_tag;
    for (int g = NG - 1; g >= 0; --g) {
      Sg[g] = (unsigned char)cur;
      cur = sup[g * 16 + cur];
    }
  }
  __syncthreads();
  for (int g = tid; g < NG; g += blockDim.x) {
    int cur = Sg[g];
    int hi = g * GRP + GRP - 1; if (hi > C - 1) hi = C - 1;
    for (int c = hi; c >= g * GRP; --c) {
      s_arr[c] = (unsigned char)cur;
      cur = maps[c * 16 + cur];
    }
  }
}

// ---------------------------------------------------------------------------
// K6: emit out[t] = st[t*16 + s_arr[t / L4]] as int32.
// ---------------------------------------------------------------------------
__global__ void k_emit(const unsigned char* __restrict__ st,
                       const unsigned char* __restrict__ s_arr,
                       int* __restrict__ out, int T) {
  int t = blockIdx.x * blockDim.x + threadIdx.x;
  if (t < T) out[t] = (int)st[(size_t)t * 16 + s_arr[t / L4]];
}

extern "C" void kernel_launch(void* const* d_in, const int* in_sizes, int n_in,
                              void* d_out, int out_size, void* d_ws, size_t ws_size,
                              hipStream_t stream) {
  const float* feats = (const float*)d_in[0];   // [1, T, 16] fp32
  const float* trans = (const float*)d_in[1];   // [16, 16]  fp32
  int* out = (int*)d_out;                       // [T] int32

  const int T  = in_sizes[0] / 16;
  const int C  = (T + L4 - 1) / L4;
  const int NG = (C + GRP - 1) / GRP;

  char* ws = (char*)d_ws;
  float* FV           = (float*)ws;                                   // (T+1)*16 floats
  unsigned char* bp   = (unsigned char*)(FV + (size_t)(T + 1) * 16);  // T*16 B
  unsigned char* st   = bp + (size_t)T * 16;                          // T*16 B
  unsigned char* maps = st + (size_t)T * 16;                          // C*16
  unsigned char* sup  = maps + (size_t)C * 16;                        // NG*16
  unsigned char* sarr = sup + (size_t)NG * 16;                        // C
  int* last_tag = (int*)(((uintptr_t)(sarr + C) + 15) & ~(uintptr_t)15);
  size_t need = (size_t)((char*)(last_tag + 1) - ws);
  if (ws_size < need) return;  // insufficient scratch -> fail visibly

  k_chain<<<1, 64, 0, stream>>>(feats, trans, FV, last_tag, T);
  k_bp<<<(T + 255) / 256, 256, 0, stream>>>(FV, trans, (uint4*)bp, T);
  k_chase<<<(C + 3) / 4, 64, 0, stream>>>(bp, st, maps, T, C);
  k_group<<<NG, 64, 0, stream>>>(maps, sup, C, NG);
  k_resolve<<<1, 128, 0, stream>>>(maps, sup, last_tag, sarr, C, NG);
  const int thr = 256;
  k_emit<<<(T + thr - 1) / thr, thr, 0, stream>>>(st, sarr, out, T);
}

// Round 5
// 87736.542 us; speedup vs baseline: 1.3539x; 1.0196x over previous
//
#include <hip/hip_runtime.h>
#include <stdint.h>

#define L4   250   // chase chunk length
#define GRP  50    // chunks per map-composition group
#define PF   16    // feat prefetch depth (named registers) in k_chain

// ---------------------------------------------------------------------------
// Exact 16-wide max-reduce via fused DPP xor-butterfly, masks {8,7,3,1}:
//   row_ror:8        == lane i^8 (within row of 16)
//   row_half_mirror  == lane i^7
//   quad_perm:[3,2,1,0] == lane i^3
//   quad_perm:[1,0,3,2] == lane i^1
// {8,7,3,1} span GF(2)^4 -> full 16-lane reduction. Verified bit-exact on HW
// (R3/R4 passed with absmax 0.0 over a 1M-step argmax-sensitive chain).
// Result (max over row i) lands in b0.
// ---------------------------------------------------------------------------
#define BTREE(b0,b1,b2,b3,b4,b5,b6,b7,b8,b9,b10,b11,b12,b13,b14,b15)          \
  asm("s_nop 1\n\t"                                                           \
      "v_max_f32_dpp %0, %8, %0  row_ror:8 row_mask:0xf bank_mask:0xf\n\t"    \
      "v_max_f32_dpp %1, %9, %1  row_ror:8 row_mask:0xf bank_mask:0xf\n\t"    \
      "v_max_f32_dpp %2, %10, %2 row_ror:8 row_mask:0xf bank_mask:0xf\n\t"    \
      "v_max_f32_dpp %3, %11, %3 row_ror:8 row_mask:0xf bank_mask:0xf\n\t"    \
      "v_max_f32_dpp %4, %12, %4 row_ror:8 row_mask:0xf bank_mask:0xf\n\t"    \
      "v_max_f32_dpp %5, %13, %5 row_ror:8 row_mask:0xf bank_mask:0xf\n\t"    \
      "v_max_f32_dpp %6, %14, %6 row_ror:8 row_mask:0xf bank_mask:0xf\n\t"    \
      "v_max_f32_dpp %7, %15, %7 row_ror:8 row_mask:0xf bank_mask:0xf\n\t"    \
      "v_max_f32_dpp %3, %4, %3  row_half_mirror row_mask:0xf bank_mask:0xf\n\t" \
      "v_max_f32_dpp %2, %5, %2  row_half_mirror row_mask:0xf bank_mask:0xf\n\t" \
      "v_max_f32_dpp %1, %6, %1  row_half_mirror row_mask:0xf bank_mask:0xf\n\t" \
      "v_max_f32_dpp %0, %7, %0  row_half_mirror row_mask:0xf bank_mask:0xf\n\t" \
      "v_max_f32_dpp %1, %2, %1  quad_perm:[3,2,1,0] row_mask:0xf bank_mask:0xf\n\t" \
      "v_max_f32_dpp %0, %3, %0  quad_perm:[3,2,1,0] row_mask:0xf bank_mask:0xf\n\t" \
      "s_nop 0\n\t"                                                           \
      "v_max_f32_dpp %0, %1, %0  quad_perm:[1,0,3,2] row_mask:0xf bank_mask:0xf" \
      : "+v"(b0), "+v"(b1), "+v"(b2), "+v"(b3),                               \
        "+v"(b4), "+v"(b5), "+v"(b6), "+v"(b7),                               \
        "+v"(b8), "+v"(b9), "+v"(b10), "+v"(b11),                             \
        "+v"(b12), "+v"(b13), "+v"(b14), "+v"(b15))

// One exact Viterbi value step. FB = prefetched feat[t][i]; u = slot index
// for immediate-offset addressing (u*64 bytes).
#define STEP(FB, u)  do {                                                     \
    float b0 = fv + tr0,  b1 = fv + tr1,  b2 = fv + tr2,  b3 = fv + tr3;      \
    float b4 = fv + tr4,  b5 = fv + tr5,  b6 = fv + tr6,  b7 = fv + tr7;      \
    float b8 = fv + tr8,  b9 = fv + tr9,  b10 = fv + tr10, b11 = fv + tr11;   \
    float b12 = fv + tr12, b13 = fv + tr13, b14 = fv + tr14, b15 = fv + tr15; \
    BTREE(b0,b1,b2,b3,b4,b5,b6,b7,b8,b9,b10,b11,b12,b13,b14,b15);             \
    fv = b0 + FB;                                                             \
    FB = pf[(u) * 16];                                                        \
    st[(u) * 16] = fv;                                                        \
  } while (0)

// ---------------------------------------------------------------------------
// K1: value-only exact Viterbi forward chain. ONE wave, fused-DPP hot loop.
// __launch_bounds__(64, 1): min 1 wave/EU -> full 512-VGPR budget. Without
// this the backend's occupancy heuristic allocated 32 VGPRs and spilled the
// ~54-reg live set to scratch, putting per-step scratch reloads + store-WAR
// waitcnts on the chain (R3/R4: ~280 cyc/step).
// Lane i (replicated x4 across the wave's four 16-lane rows) holds fv[i].
// Streams FV[t] (fv entering step t); FV[0] = zeros.
// ---------------------------------------------------------------------------
__global__ __launch_bounds__(64, 1)
void k_chain(const float* __restrict__ feats, const float* __restrict__ trans,
             float* __restrict__ FV, int* __restrict__ last_tag, int T) {
  const int l = threadIdx.x;
  const int i = l & 15;

  // tr_d = trans[(i^d)][i]
  const float tr0  = trans[((i ^ 0)  << 4) + i];
  const float tr1  = trans[((i ^ 1)  << 4) + i];
  const float tr2  = trans[((i ^ 2)  << 4) + i];
  const float tr3  = trans[((i ^ 3)  << 4) + i];
  const float tr4  = trans[((i ^ 4)  << 4) + i];
  const float tr5  = trans[((i ^ 5)  << 4) + i];
  const float tr6  = trans[((i ^ 6)  << 4) + i];
  const float tr7  = trans[((i ^ 7)  << 4) + i];
  const float tr8  = trans[((i ^ 8)  << 4) + i];
  const float tr9  = trans[((i ^ 9)  << 4) + i];
  const float tr10 = trans[((i ^ 10) << 4) + i];
  const float tr11 = trans[((i ^ 11) << 4) + i];
  const float tr12 = trans[((i ^ 12) << 4) + i];
  const float tr13 = trans[((i ^ 13) << 4) + i];
  const float tr14 = trans[((i ^ 14) << 4) + i];
  const float tr15 = trans[((i ^ 15) << 4) + i];

  float fv = 0.0f;
  FV[i] = 0.0f;  // FV[0] = init (replicated lanes write same value/addr)

  // 16 named prefetch registers: f_u = feats[u][i]
  #define LD0(u) ((u) < T ? feats[(u) * 16 + i] : 0.0f)
  float f0 = LD0(0),  f1 = LD0(1),  f2 = LD0(2),  f3 = LD0(3);
  float f4 = LD0(4),  f5 = LD0(5),  f6 = LD0(6),  f7 = LD0(7);
  float f8 = LD0(8),  f9 = LD0(9),  f10 = LD0(10), f11 = LD0(11);
  float f12 = LD0(12), f13 = LD0(13), f14 = LD0(14), f15 = LD0(15);
  #undef LD0

  const float* pf = feats + (size_t)PF * 16 + i;  // prefetch base (t+PF)
  float*       st = FV + 16 + i;                  // store base (FV[t+1])

  const int Tm = (T >= 2 * PF) ? ((T - PF) / PF) * PF : 0;

  for (int t = 0; t < Tm; t += PF) {
    STEP(f0, 0);   STEP(f1, 1);   STEP(f2, 2);   STEP(f3, 3);
    STEP(f4, 4);   STEP(f5, 5);   STEP(f6, 6);   STEP(f7, 7);
    STEP(f8, 8);   STEP(f9, 9);   STEP(f10, 10); STEP(f11, 11);
    STEP(f12, 12); STEP(f13, 13); STEP(f14, 14); STEP(f15, 15);
    pf += PF * 16;
    st += PF * 16;
  }
  for (int t = Tm; t < T; ++t) {  // tail: direct loads
    float b0 = fv + tr0,  b1 = fv + tr1,  b2 = fv + tr2,  b3 = fv + tr3;
    float b4 = fv + tr4,  b5 = fv + tr5,  b6 = fv + tr6,  b7 = fv + tr7;
    float b8 = fv + tr8,  b9 = fv + tr9,  b10 = fv + tr10, b11 = fv + tr11;
    float b12 = fv + tr12, b13 = fv + tr13, b14 = fv + tr14, b15 = fv + tr15;
    BTREE(b0,b1,b2,b3,b4,b5,b6,b7,b8,b9,b10,b11,b12,b13,b14,b15);
    fv = b0 + feats[(size_t)t * 16 + i];
    FV[(size_t)(t + 1) * 16 + i] = fv;
  }

  // last_tag = argmax (first-index tie-break) of final fv
  float bv = __shfl(fv, 0, 64); int bi = 0;
  #pragma unroll
  for (int p = 1; p < 16; ++p) {
    float ov = __shfl(fv, p, 64);
    if (ov > bv) { bv = ov; bi = p; }
  }
  if (l == 0) *last_tag = bi;
}

// ---------------------------------------------------------------------------
// K2: parallel backpointer recompute. Thread per t. Bit-identical argmax
// (strict >, first-index) from exact FV[t].
// ---------------------------------------------------------------------------
__global__ __launch_bounds__(256)
void k_bp(const float* __restrict__ FV, const float* __restrict__ trans,
          uint4* __restrict__ bp, int T) {
  __shared__ float str[256];
  const int tid = threadIdx.x;
  str[tid] = trans[tid];
  __syncthreads();
  const int t = blockIdx.x * blockDim.x + tid;
  if (t >= T) return;
  const float4* fr = (const float4*)(FV + (size_t)t * 16);
  float4 q0 = fr[0], q1 = fr[1], q2 = fr[2], q3 = fr[3];
  float fv[16] = {q0.x, q0.y, q0.z, q0.w, q1.x, q1.y, q1.z, q1.w,
                  q2.x, q2.y, q2.z, q2.w, q3.x, q3.y, q3.z, q3.w};
  uint32_t w[4];
  #pragma unroll
  for (int g = 0; g < 4; ++g) {
    uint32_t word = 0;
    #pragma unroll
    for (int s = 0; s < 4; ++s) {
      const int nn = 4 * g + s;
      float best = fv[0] + str[nn * 16 + 0];
      int bi = 0;
      #pragma unroll
      for (int p = 1; p < 16; ++p) {
        float v = fv[p] + str[nn * 16 + p];
        if (v > best) { best = v; bi = p; }
      }
      word |= (uint32_t)bi << (8 * s);
    }
    w[g] = word;
  }
  bp[t] = make_uint4(w[0], w[1], w[2], w[3]);
}

// ---------------------------------------------------------------------------
// K3: per-chunk 16-hypothesis backtrack (exact integer pointer chase).
// ---------------------------------------------------------------------------
__global__ __launch_bounds__(64)
void k_chase(const unsigned char* __restrict__ bp, unsigned char* __restrict__ st,
             unsigned char* __restrict__ maps, int T, int C) {
  const int tid = threadIdx.x;
  const int chunk = blockIdx.x * 4 + (tid >> 4);
  const int h = tid & 15;
  if (chunk >= C) return;
  const int a = chunk * L4;
  int b = a + L4; if (b > T) b = T;
  int cur = h;
  for (int t = b - 1; t >= a; --t) {
    cur = bp[(size_t)t * 16 + cur];
    st[(size_t)t * 16 + h] = (unsigned char)cur;
  }
  maps[chunk * 16 + h] = (unsigned char)cur;
}

// ---------------------------------------------------------------------------
// K4: compose GRP consecutive chunk maps into one super-map per group.
// ---------------------------------------------------------------------------
__global__ __launch_bounds__(64)
void k_group(const unsigned char* __restrict__ maps, unsigned char* __restrict__ sup,
             int C, int NG) {
  const int g = blockIdx.x;
  const int e = threadIdx.x;
  if (g >= NG || e >= 16) return;
  int hi = g * GRP + GRP - 1; if (hi > C - 1) hi = C - 1;
  int cur = e;
  for (int c = hi; c >= g * GRP; --c) cur = maps[c * 16 + cur];
  sup[g * 16 + e] = (unsigned char)cur;
}

// ---------------------------------------------------------------------------
// K5: resolve true tag at every chunk's end boundary.
// ---------------------------------------------------------------------------
__global__ __launch_bounds__(128)
void k_resolve(const unsigned char* __restrict__ maps, const unsigned char* __restrict__ sup,
               const int* __restrict__ last_tag, unsigned char* __restrict__ s_arr,
               int C, int NG) {
  __shared__ unsigned char Sg[4096];
  const int tid = threadIdx.x;
  if (tid == 0) {
    int cur = *last_tag;
    for (int g = NG - 1; g >= 0; --g) {
      Sg[g] = (unsigned char)cur;
      cur = sup[g * 16 + cur];
    }
  }
  __syncthreads();
  for (int g = tid; g < NG; g += blockDim.x) {
    int cur = Sg[g];
    int hi = g * GRP + GRP - 1; if (hi > C - 1) hi = C - 1;
    for (int c = hi; c >= g * GRP; --c) {
      s_arr[c] = (unsigned char)cur;
      cur = maps[c * 16 + cur];
    }
  }
}

// ---------------------------------------------------------------------------
// K6: emit out[t] = st[t*16 + s_arr[t / L4]] as int32.
// ---------------------------------------------------------------------------
__global__ void k_emit(const unsigned char* __restrict__ st,
                       const unsigned char* __restrict__ s_arr,
                       int* __restrict__ out, int T) {
  int t = blockIdx.x * blockDim.x + threadIdx.x;
  if (t < T) out[t] = (int)st[(size_t)t * 16 + s_arr[t / L4]];
}

extern "C" void kernel_launch(void* const* d_in, const int* in_sizes, int n_in,
                              void* d_out, int out_size, void* d_ws, size_t ws_size,
                              hipStream_t stream) {
  const float* feats = (const float*)d_in[0];   // [1, T, 16] fp32
  const float* trans = (const float*)d_in[1];   // [16, 16]  fp32
  int* out = (int*)d_out;                       // [T] int32

  const int T  = in_sizes[0] / 16;
  const int C  = (T + L4 - 1) / L4;
  const int NG = (C + GRP - 1) / GRP;

  char* ws = (char*)d_ws;
  float* FV           = (float*)ws;                                   // (T+1)*16 floats
  unsigned char* bp   = (unsigned char*)(FV + (size_t)(T + 1) * 16);  // T*16 B
  unsigned char* st   = bp + (size_t)T * 16;                          // T*16 B
  unsigned char* maps = st + (size_t)T * 16;                          // C*16
  unsigned char* sup  = maps + (size_t)C * 16;                        // NG*16
  unsigned char* sarr = sup + (size_t)NG * 16;                        // C
  int* last_tag = (int*)(((uintptr_t)(sarr + C) + 15) & ~(uintptr_t)15);
  size_t need = (size_t)((char*)(last_tag + 1) - ws);
  if (ws_size < need) return;  // insufficient scratch -> fail visibly

  k_chain<<<1, 64, 0, stream>>>(feats, trans, FV, last_tag, T);
  k_bp<<<(T + 255) / 256, 256, 0, stream>>>(FV, trans, (uint4*)bp, T);
  k_chase<<<(C + 3) / 4, 64, 0, stream>>>(bp, st, maps, T, C);
  k_group<<<NG, 64, 0, stream>>>(maps, sup, C, NG);
  k_resolve<<<1, 128, 0, stream>>>(maps, sup, last_tag, sarr, C, NG);
  const int thr = 256;
  k_emit<<<(T + thr - 1) / thr, thr, 0, stream>>>(st, sarr, out, T);
}